// Round 1
// 326.331 us; speedup vs baseline: 1.1183x; 1.1183x over previous
//
#include <hip/hip_runtime.h>

// PINNLayer — NN=100000, NE=3200000. fp32 in, fp32 out.
// d_out fp32: [ result (NN) | out2 (NE,3) rows = [src,dst,val] ].
//
// Round-6: accum was latency-bound (VALUBusy 17%, occ 35%, HBM 2.5%) with a
// memory-side u64-atomic flush (1.7M RMWs) and a dependent record->conc[s]
// gather chain. New full path:
//   P1 edge_conv: conv + out2 + bc[e]=val*conc[src]  (gather moved here,
//      hidden under conv; accum loop now has only independent loads).
//   P2 accum_f: 7 windows x 16384 nodes (128KB LDS) x 32 slices = 224 blocks;
//      4-way batched scan; flush = PLAIN coalesced float4 stores of per-slice
//      partials (ZERO global atomics, no fixed-point quantization).
//      XCD swizzle co-locates a slice's 7 window-readers on one XCD (L2 reuse).
//   P3 node_final_f: sum 32 partials + compose.
// Fallback to the proven round-5 pipeline if ws_size < ~43MB.

#define WSH  14
#define WSZ  16384      // nodes per window (128KB LDS for two fp32 tables)
#define PBF  32         // record slices (must be multiple of 8 for the swizzle)

// old-path constants (fallback)
#define OWSH 13
#define OWSZ 8192
#define OPB  16
#define OFPS 8192.0f
#define OQBIAS (1 << 20)
#define OQCLMP ((1 << 19) - 1)

// ---------------------------------------------------------------------------
__global__ __launch_bounds__(256) void prep(
    const float* __restrict__ od,
    float* __restrict__ conc,
    unsigned long long* __restrict__ acc,
    int n_nodes)
{
    int n = blockIdx.x * blockDim.x + threadIdx.x;
    if (n >= n_nodes) return;
    conc[n] = od[(long long)n * 48 + 45];   // origin_data[n,15,0]
    if (acc) acc[n] = 0ULL;
}

// ---------------------------------------------------------------------------
// P1: conv + out2 (+ optional bc = val*conc[src] staging).
// val[e] = b + sum_{j<36} flow[e*12+j] * w_re[j],
//   w_re[kh*12+kw*4+i] = conv_w[i*9+kh*3+kw]
__global__ __launch_bounds__(256) void edge_conv(
    const float* __restrict__ flow, const int* __restrict__ ei,
    const float* __restrict__ conv_w, const float* __restrict__ conv_b,
    const float* __restrict__ conc,
    float* __restrict__ out2, float* __restrict__ bcv, int n_edges)
{
    __shared__ float w[40];
    int t = threadIdx.x;
    if (t < 36) {
        int i  = t & 3;
        int kw = (t >> 2) % 3;
        int kh = t / 12;
        w[t] = conv_w[i * 9 + kh * 3 + kw];
    }
    if (t == 36) w[36] = conv_b[0];
    __syncthreads();

    int e = blockIdx.x * blockDim.x + t;
    if (e >= n_edges) return;

    int s = ei[e];
    int d = ei[n_edges + e];
    float cs = bcv ? conc[s] : 0.0f;    // L2-resident gather (400KB), full path only

    const float4* fp = (const float4*)(flow + (long long)e * 12);
    float acc = w[36];
#pragma unroll
    for (int q = 0; q < 9; ++q) {
        float4 v = fp[q];
        acc = fmaf(v.x, w[q * 4 + 0], acc);
        acc = fmaf(v.y, w[q * 4 + 1], acc);
        acc = fmaf(v.z, w[q * 4 + 2], acc);
        acc = fmaf(v.w, w[q * 4 + 3], acc);
    }

    float* o = out2 + (long long)e * 3;
    o[0] = (float)s;
    o[1] = (float)d;
    o[2] = acc;
    if (bcv) bcv[e] = acc * cs;
}

// ---------------------------------------------------------------------------
// P2 (full): windowed LDS accumulation, atomic-free flush to per-slice partials.
__global__ __launch_bounds__(1024) void accum_f(
    const float* __restrict__ out2,
    const float* __restrict__ bcv,
    float* __restrict__ pA,
    float* __restrict__ pB,
    int n_edges, int n_win, int stride)
{
    __shared__ float tA[WSZ];
    __shared__ float tB[WSZ];

    // XCD co-location: all n_win window-blocks of a slice share one XCD's L2.
    // (xcd = blockIdx % 8 mapping; if HW maps differently this is perf-only.)
    const int xcd = blockIdx.x & 7;
    const int i   = blockIdx.x >> 3;
    const int j   = i / n_win;                 // 0 .. PBF/8-1
    const int sl  = xcd * (PBF >> 3) + j;      // slice id
    const int w   = i - j * n_win;             // window id

    const int t = threadIdx.x;
    for (int k = t; k < WSZ; k += 1024) { tA[k] = 0.f; tB[k] = 0.f; }
    __syncthreads();

    const long long e0 = (long long)sl * n_edges / PBF;
    const long long e1 = (long long)(sl + 1) * n_edges / PBF;

#define PROC(fs, fd, vv, bb)                                          \
    {                                                                  \
        int s_ = (int)(fs), d_ = (int)(fd);                            \
        if (s_ != d_) {                                                \
            if ((s_ >> WSH) == w) atomicAdd(&tA[s_ & (WSZ - 1)], (vv));\
            if ((d_ >> WSH) == w) atomicAdd(&tB[d_ & (WSZ - 1)], (bb));\
        }                                                              \
    }

    long long e = e0 + t;
    // 4-way batch: 8 independent loads in flight before any dependent use.
    for (; e + 3 * 1024 < e1; e += 4 * 1024) {
        const float* r  = out2 + e * 3;
        const float* bb = bcv + e;
        float fs0 = r[0],    fd0 = r[1],    v0 = r[2];
        float fs1 = r[3072], fd1 = r[3073], v1 = r[3074];
        float fs2 = r[6144], fd2 = r[6145], v2 = r[6146];
        float fs3 = r[9216], fd3 = r[9217], v3 = r[9218];
        float b0 = bb[0], b1 = bb[1024], b2 = bb[2048], b3 = bb[3072];
        PROC(fs0, fd0, v0, b0);
        PROC(fs1, fd1, v1, b1);
        PROC(fs2, fd2, v2, b2);
        PROC(fs3, fd3, v3, b3);
    }
    for (; e < e1; e += 1024) {
        const float* r = out2 + e * 3;
        float fs = r[0], fd = r[1], vv = r[2];
        float bb = bcv[e];
        PROC(fs, fd, vv, bb);
    }
#undef PROC
    __syncthreads();

    // Flush: plain coalesced float4 stores — no atomics, no quantization.
    float* dA = pA + (long long)sl * stride + ((long long)w << WSH);
    float* dB = pB + (long long)sl * stride + ((long long)w << WSH);
    for (int k = t; k < (WSZ >> 2); k += 1024) {
        ((float4*)dA)[k] = ((const float4*)tA)[k];
        ((float4*)dB)[k] = ((const float4*)tB)[k];
    }
}

// ---------------------------------------------------------------------------
// P3 (full): reduce PBF partials and compose result.
__global__ __launch_bounds__(256) void node_final_f(
    const float* __restrict__ od,
    const float* __restrict__ conc,
    const float* __restrict__ pA,
    const float* __restrict__ pB,
    float* __restrict__ out, int n_nodes, int stride)
{
    int n = blockIdx.x * blockDim.x + threadIdx.x;
    if (n >= n_nodes) return;

    float a0 = 0.f, a1 = 0.f, a2 = 0.f, a3 = 0.f;
    float b0 = 0.f, b1 = 0.f, b2 = 0.f, b3 = 0.f;
#pragma unroll
    for (int sl = 0; sl < PBF; sl += 4) {
        a0 += pA[(long long)(sl + 0) * stride + n];
        a1 += pA[(long long)(sl + 1) * stride + n];
        a2 += pA[(long long)(sl + 2) * stride + n];
        a3 += pA[(long long)(sl + 3) * stride + n];
        b0 += pB[(long long)(sl + 0) * stride + n];
        b1 += pB[(long long)(sl + 1) * stride + n];
        b2 += pB[(long long)(sl + 2) * stride + n];
        b3 += pB[(long long)(sl + 3) * stride + n];
    }
    float a = (a0 + a1) + (a2 + a3);
    float b = (b0 + b1) + (b2 + b3);

    long long bi = (long long)n * 48 + 45;
    float c  = conc[n];
    float p  = od[bi + 1];
    float is = 1.0f / od[bi + 2];

    float r = c;
    if (n != n_nodes - 1)
        r += (b - a * c) * is + 0.0052f * p * is;
    out[n] = r;
}

// ---------------------------------------------------------------------------
// Fallback path (round-5 proven): u64 fixed-point atomic flush.
__global__ __launch_bounds__(1024) void accum_o(
    const float* __restrict__ out2,
    const float* __restrict__ conc,
    unsigned long long* __restrict__ acc,
    int n_edges, int n_nodes)
{
    __shared__ float tA[OWSZ];
    __shared__ float tB[OWSZ];

    const int w    = blockIdx.x / OPB;
    const int sl   = blockIdx.x % OPB;
    const int base = w << OWSH;

    for (int i = threadIdx.x; i < OWSZ; i += 1024) { tA[i] = 0.f; tB[i] = 0.f; }
    __syncthreads();

    const long long e0 = (long long)sl * n_edges / OPB;
    const long long e1 = (long long)(sl + 1) * n_edges / OPB;
    for (long long e = e0 + threadIdx.x; e < e1; e += 1024) {
        const float* r = out2 + e * 3;
        float fs = r[0], fd = r[1], v = r[2];
        int s = (int)fs, d = (int)fd;
        if (s == d) continue;
        if ((s >> OWSH) == w) atomicAdd(&tA[s - base], v);
        if ((d >> OWSH) == w) atomicAdd(&tB[d - base], v * conc[s]);
    }
    __syncthreads();

    for (int i = threadIdx.x; i < OWSZ; i += 1024) {
        int n = base + i;
        if (n >= n_nodes) continue;
        float a = tA[i], b = tB[i];
        if (a == 0.f && b == 0.f) continue;
        int qa = __float2int_rn(a * OFPS);
        int qb = __float2int_rn(b * OFPS);
        qa = min(max(qa, -OQCLMP), OQCLMP);
        qb = min(max(qb, -OQCLMP), OQCLMP);
        unsigned long long enc =
            ((unsigned long long)(unsigned)(qa + OQBIAS) << 37) +
            ((unsigned long long)(unsigned)(qb + OQBIAS) << 10) + 1ULL;
        atomicAdd(acc + n, enc);
    }
}

__global__ __launch_bounds__(256) void node_final_o(
    const float* __restrict__ od,
    const float* __restrict__ conc,
    const unsigned long long* __restrict__ acc,
    float* __restrict__ out, int n_nodes)
{
    int n = blockIdx.x * blockDim.x + threadIdx.x;
    if (n >= n_nodes) return;

    unsigned long long t = acc[n];
    long long cnt = (long long)(t & 1023ULL);
    unsigned long long t2 = t >> 10;
    long long sbr = (long long)(t2 & ((1ULL << 27) - 1));
    long long sar = (long long)(t2 >> 27);
    float a = (float)(sar - cnt * OQBIAS) * (1.0f / OFPS);
    float b = (float)(sbr - cnt * OQBIAS) * (1.0f / OFPS);

    long long bi = (long long)n * 48 + 45;
    float c  = conc[n];
    float p  = od[bi + 1];
    float is = 1.0f / od[bi + 2];

    float r = c;
    if (n != n_nodes - 1)
        r += (b - a * c) * is + 0.0052f * p * is;
    out[n] = r;
}

// ---------------------------------------------------------------------------
extern "C" void kernel_launch(void* const* d_in, const int* in_sizes, int n_in,
                              void* d_out, int out_size, void* d_ws, size_t ws_size,
                              hipStream_t stream) {
    const float* od   = (const float*)d_in[0];
    const float* flow = (const float*)d_in[1];
    const float* cw   = (const float*)d_in[2];
    const float* cb   = (const float*)d_in[3];
    const int*   ei   = (const int*)d_in[4];

    const int n_nodes = in_sizes[0] / 48;
    const int n_edges = in_sizes[4] / 2;

    float* out_res = (float*)d_out;        // (NN,)
    float* out2    = out_res + n_nodes;    // (NE,3) — also the record staging

    dim3 blk(256);
    dim3 grid_nodes((n_nodes + 255) / 256);
    dim3 grid_edges((n_edges + 255) / 256);

    // --- full-path workspace layout -------------------------------------
    const int n_win  = (n_nodes + WSZ - 1) >> WSH;     // 7
    const int stride = n_win << WSH;                   // padded node count
    size_t off = 0;
    size_t o_conc = off; off += (((size_t)n_nodes * 4) + 255) & ~255ULL;
    size_t o_bc   = off; off += (((size_t)n_edges * 4) + 255) & ~255ULL;
    size_t o_pA   = off; off += (((size_t)PBF * stride * 4) + 255) & ~255ULL;
    size_t o_pB   = off; off += (((size_t)PBF * stride * 4) + 255) & ~255ULL;
    const bool full = (ws_size >= off);

    float* conc = (float*)((char*)d_ws + o_conc);

    if (full) {
        float* bcv = (float*)((char*)d_ws + o_bc);
        float* pA  = (float*)((char*)d_ws + o_pA);
        float* pB  = (float*)((char*)d_ws + o_pB);

        prep<<<grid_nodes, blk, 0, stream>>>(od, conc, nullptr, n_nodes);
        edge_conv<<<grid_edges, blk, 0, stream>>>(flow, ei, cw, cb, conc,
                                                  out2, bcv, n_edges);
        accum_f<<<dim3(n_win * PBF), dim3(1024), 0, stream>>>(
            out2, bcv, pA, pB, n_edges, n_win, stride);
        node_final_f<<<grid_nodes, blk, 0, stream>>>(od, conc, pA, pB,
                                                     out_res, n_nodes, stride);
    } else {
        // round-5 pipeline
        unsigned long long* acc =
            (unsigned long long*)((char*)d_ws + (((size_t)n_nodes * 4 + 7) / 8 * 8));
        const int n_win_o = (n_nodes + OWSZ - 1) >> OWSH;

        prep<<<grid_nodes, blk, 0, stream>>>(od, conc, acc, n_nodes);
        edge_conv<<<grid_edges, blk, 0, stream>>>(flow, ei, cw, cb, conc,
                                                  out2, nullptr, n_edges);
        accum_o<<<dim3(n_win_o * OPB), dim3(1024), 0, stream>>>(
            out2, conc, acc, n_edges, n_nodes);
        node_final_o<<<grid_nodes, blk, 0, stream>>>(od, conc, acc,
                                                     out_res, n_nodes);
    }
}